// Round 3
// baseline (1836.222 us; speedup 1.0000x reference)
//
#include <hip/hip_runtime.h>
#include <hip/hip_bf16.h>

#define B_ROWS 1024
#define D_DIM 256
#define Q_N 65536
#define K_TOP 200
#define N_CLASSES 10
#define INV_T 14.2857142857142857f /* 1/0.07 */

typedef unsigned int u32;
typedef unsigned short u16;
typedef unsigned long long u64;

using bf16x8 = __attribute__((ext_vector_type(8))) __bf16;
using f32x4  = __attribute__((ext_vector_type(4))) float;

// ---- helpers ----------------------------------------------------------------

// order-preserving float->uint key (descending float == descending key)
__device__ __forceinline__ u32 fkey(float f) {
  u32 u = __float_as_uint(f);
  return (u >> 31) ? ~u : (u | 0x80000000u);
}
__device__ __forceinline__ float funkey(u32 u) {
  return __uint_as_float((u >> 31) ? (u & 0x7fffffffu) : ~u);
}
__device__ __forceinline__ u16 bf16_rn(float f) {
  u32 u = __float_as_uint(f);
  u32 r = (u + 0x7fffu + ((u >> 16) & 1u)) >> 16;
  return (u16)r;
}
// f ~= hi + lo with hi,lo bf16 (error ~2^-16 relative)
__device__ __forceinline__ void split2(float f, u16& h, u16& l) {
  u16 hh = bf16_rn(f);
  float hf = __uint_as_float(((u32)hh) << 16);
  h = hh;
  l = bf16_rn(f - hf);
}

__device__ __forceinline__ void gl16(const void* g, void* l) {
  __builtin_amdgcn_global_load_lds((const __attribute__((address_space(1))) u32*)g,
                                   (__attribute__((address_space(3))) u32*)l, 16, 0, 0);
}

// ---- kernel 1: x row-normalize + bf16 hi/lo split ---------------------------
__global__ __launch_bounds__(256) void xnorm_k(const float* __restrict__ x,
                                               u16* __restrict__ xh, u16* __restrict__ xl) {
  int row = blockIdx.x, t = threadIdx.x;
  int lane = t & 63, w = t >> 6;
  float v = x[row * D_DIM + t];
  float s = v * v;
  for (int o = 32; o > 0; o >>= 1) s += __shfl_down(s, o);
  __shared__ float ws[4];
  if (lane == 0) ws[w] = s;
  __syncthreads();
  if (t == 0) ws[0] = ws[0] + ws[1] + ws[2] + ws[3];
  __syncthreads();
  float inv = 1.0f / fmaxf(sqrtf(ws[0]), 1e-12f);
  u16 h, l;
  split2(v * inv, h, l);
  xh[row * D_DIM + t] = h;
  xl[row * D_DIM + t] = l;
}

// ---- kernel 2: memory bf16 hi/lo split --------------------------------------
__global__ __launch_bounds__(256) void mdecomp_k(const float4* __restrict__ m,
                                                 ushort4* __restrict__ mh,
                                                 ushort4* __restrict__ ml, int n4) {
  int i = blockIdx.x * blockDim.x + threadIdx.x;
  int stride = gridDim.x * blockDim.x;
  for (; i < n4; i += stride) {
    float4 v = m[i];
    ushort4 h, l;
    split2(v.x, h.x, l.x);
    split2(v.y, h.y, l.y);
    split2(v.z, h.z, l.z);
    split2(v.w, h.w, l.w);
    mh[i] = h;
    ml[i] = l;
  }
}

// ---- kernel 3: dist = A*B^T via bf16x3 MFMA (128x128 tile, BK=32) -----------
// 1D grid, XCD-chunked swizzle: row-tile index fastest so the mt blocks sharing
// a B col-tile are swz-adjacent -> same XCD -> B served from that XCD's L2.
// LDS chunk-XOR swizzle (chunk ^= (row>>1)&3, 16B chunks in 64B rows): each
// 8-lane ds_read_b128 phase group covers all 32 banks exactly once.
__global__ __launch_bounds__(256) void gemm3_k(const u16* __restrict__ Ah, const u16* __restrict__ Al,
                                               const u16* __restrict__ Bh, const u16* __restrict__ Bl,
                                               float* __restrict__ dist, int row0, int rows,
                                               int mt, int nwg) {
  __shared__ u16 sAh[4096], sAl[4096], sBh[4096], sBl[4096];  // 4 x 8KB
  int tid = threadIdx.x;
  int lane = tid & 63, wid = tid >> 6;
  int wr = wid >> 1, wc = wid & 1;

  int bid = blockIdx.x;
  int swz = (bid & 7) * (nwg >> 3) + (bid >> 3);  // nwg % 8 == 0 guaranteed
  int trow0 = (swz % mt) << 7;
  int col0 = (swz / mt) << 7;

  // staging: linear LDS dest (global_load_lds contract); bank-swizzle applied by
  // permuting the 16B chunk each lane fetches from GLOBAL.
  int r_s = wid * 32 + (lane >> 2);                       // local row this lane fills
  int c_s = (((lane & 3) ^ ((lane >> 3) & 3)) << 3);      // swizzled chunk -> elem offset
  int ar0 = row0 + trow0 + r_s;
  int ar1 = ar0 + 16;
  ar0 = min(ar0, B_ROWS - 1);  // tail tiles: clamp (store-guarded anyway)
  ar1 = min(ar1, B_ROWS - 1);
  int br0 = col0 + r_s, br1 = br0 + 16;

  // fragment addressing: row=lane&15(+16m), k-chunk fq ^ ((fr>>1)&3)
  int fr = lane & 15, fq = lane >> 4;
  int cswz = (fq ^ ((fr >> 1) & 3)) * 8;
  int a_off0 = (wr * 64 + fr) * 32 + cswz;
  int b_off0 = (wc * 64 + fr) * 32 + cswz;

  f32x4 acc[4][4] = {};

  for (int kt = 0; kt < 8; ++kt) {
    int k0 = kt * 32;
    gl16(Ah + (size_t)ar0 * D_DIM + k0 + c_s, &sAh[wid * 1024]);
    gl16(Ah + (size_t)ar1 * D_DIM + k0 + c_s, &sAh[wid * 1024 + 512]);
    gl16(Al + (size_t)ar0 * D_DIM + k0 + c_s, &sAl[wid * 1024]);
    gl16(Al + (size_t)ar1 * D_DIM + k0 + c_s, &sAl[wid * 1024 + 512]);
    gl16(Bh + (size_t)br0 * D_DIM + k0 + c_s, &sBh[wid * 1024]);
    gl16(Bh + (size_t)br1 * D_DIM + k0 + c_s, &sBh[wid * 1024 + 512]);
    gl16(Bl + (size_t)br0 * D_DIM + k0 + c_s, &sBl[wid * 1024]);
    gl16(Bl + (size_t)br1 * D_DIM + k0 + c_s, &sBl[wid * 1024 + 512]);
    __syncthreads();

    bf16x8 ah[4], al[4], bh[4], bl[4];
#pragma unroll
    for (int m = 0; m < 4; ++m) {
      ah[m] = *(const bf16x8*)&sAh[a_off0 + m * 512];
      al[m] = *(const bf16x8*)&sAl[a_off0 + m * 512];
    }
#pragma unroll
    for (int n = 0; n < 4; ++n) {
      bh[n] = *(const bf16x8*)&sBh[b_off0 + n * 512];
      bl[n] = *(const bf16x8*)&sBl[b_off0 + n * 512];
    }
#pragma unroll
    for (int m = 0; m < 4; ++m)
#pragma unroll
      for (int n = 0; n < 4; ++n) {
        acc[m][n] = __builtin_amdgcn_mfma_f32_16x16x32_bf16(ah[m], bh[n], acc[m][n], 0, 0, 0);
        acc[m][n] = __builtin_amdgcn_mfma_f32_16x16x32_bf16(ah[m], bl[n], acc[m][n], 0, 0, 0);
        acc[m][n] = __builtin_amdgcn_mfma_f32_16x16x32_bf16(al[m], bh[n], acc[m][n], 0, 0, 0);
      }
    __syncthreads();
  }

  // C/D layout (m89/m91): col = lane&15, row = (lane>>4)*4 + reg
#pragma unroll
  for (int m = 0; m < 4; ++m) {
    int rr = trow0 + wr * 64 + m * 16 + fq * 4;
#pragma unroll
    for (int n = 0; n < 4; ++n) {
      int cc = col0 + wc * 64 + n * 16 + fr;
#pragma unroll
      for (int r = 0; r < 4; ++r) {
        if (rr + r < rows) dist[(size_t)(rr + r) * Q_N + cc] = acc[m][n][r];
      }
    }
  }
}

// ---- kernel 4: fused top-K + softmax class scores, one pass over dist -------
// One block (1024 thr) per row. Sample 4096 elems -> coarse key threshold
// (expected ~1024 survivors, P[<200] ~ 0, deterministic retry), collect
// candidate (key,idx) pairs in LDS during the single full read, then rank all
// candidates directly (O(c^2) LDS-broadcast) and accumulate class scores.
__global__ __launch_bounds__(1024) void topk_k(const float* __restrict__ dist,
                                               const int* __restrict__ labels,
                                               float* __restrict__ out, int row0) {
  constexpr int CAP = 6144;
  constexpr u32 ST = 64;  // sample count target (sample=1/16 -> E[true]=1024)
  __shared__ u32 cand_key[CAP];   // 24 KB
  __shared__ u32 cand_idx[CAP];   // 24 KB
  __shared__ u32 shist[1024];     // 4 KB
  __shared__ u32 wtot[16];
  __shared__ float cls[16];
  __shared__ float den_s;
  __shared__ u32 cnt_s, thr_s, maxk_s;

  const int tid = threadIdx.x;
  const int lane = tid & 63, w = tid >> 6;
  const int row = blockIdx.x;
  const float4* dp = (const float4*)(dist + (size_t)row * Q_N);

  // ---- phase 0: sample -> coarse threshold key ----
  shist[tid] = 0;
  if (tid < 16) cls[tid] = 0.f;
  if (tid == 0) { den_s = 0.f; maxk_s = 0; }
  __syncthreads();
  float4 sv = dp[tid << 4];
  atomicAdd(&shist[fkey(sv.x) >> 22], 1u);
  atomicAdd(&shist[fkey(sv.y) >> 22], 1u);
  atomicAdd(&shist[fkey(sv.z) >> 22], 1u);
  atomicAdd(&shist[fkey(sv.w) >> 22], 1u);
  __syncthreads();
  // hierarchical suffix scan: in-wave shfl suffix + 16 wave totals
  u32 hv = shist[tid];
  u32 sfx = hv;
#pragma unroll
  for (int off = 1; off < 64; off <<= 1) {
    u32 t = __shfl_down(sfx, off);
    sfx += (lane + off < 64) ? t : 0u;
  }
  if (lane == 0) wtot[w] = sfx;
  __syncthreads();
  u32 woff = 0;
  for (int j = w + 1; j < 16; ++j) woff += wtot[j];
  u32 S = sfx + woff;  // suffix sum including own bin
  if (S >= ST && S - hv < ST) thr_s = (u32)tid;
  __syncthreads();
  u32 tkey = thr_s << 22;

  // ---- phase 1: single full read, collect candidates >= tkey ----
  int attempt = 0;
  u32 c;
  while (true) {
    if (tid == 0) cnt_s = 0;
    __syncthreads();
#pragma unroll
    for (int b = 0; b < 4; ++b) {
      float4 v0 = dp[tid + ((b * 4 + 0) << 10)];
      float4 v1 = dp[tid + ((b * 4 + 1) << 10)];
      float4 v2 = dp[tid + ((b * 4 + 2) << 10)];
      float4 v3 = dp[tid + ((b * 4 + 3) << 10)];
      float4 vv[4] = {v0, v1, v2, v3};
#pragma unroll
      for (int u = 0; u < 4; ++u) {
        int gi0 = (tid + ((b * 4 + u) << 10)) << 2;
        float fv[4] = {vv[u].x, vv[u].y, vv[u].z, vv[u].w};
#pragma unroll
        for (int j = 0; j < 4; ++j) {
          u32 k = fkey(fv[j]);
          if (k >= tkey) {
            u32 p = atomicAdd(&cnt_s, 1u);
            if (p < CAP) { cand_key[p] = k; cand_idx[p] = (u32)(gi0 + j); }
            atomicMax(&maxk_s, k);
          }
        }
      }
    }
    __syncthreads();
    c = cnt_s;
    if ((c >= K_TOP && c <= CAP) || ++attempt >= 8) break;
    if (tid == 0) thr_s += (c > CAP) ? 1u : (u32)-1;
    __syncthreads();
    tkey = thr_s << 22;
  }
  if (c > CAP) c = CAP;

  // ---- phase 2: exact rank via LDS broadcast, accumulate top-K ----
  float dmax = funkey(maxk_s);
  for (u32 i = tid; i < c; i += 1024) {
    u32 k = cand_key[i];
    u32 gi = cand_idx[i];
    int r = 0;
    for (u32 j = 0; j < c; ++j) {
      u32 kj = cand_key[j];
      r += (kj > k || (kj == k && cand_idx[j] < gi)) ? 1 : 0;
    }
    if (r < K_TOP) {  // exact rank; ties broken by smaller index (lax.top_k order)
      float wgt = __expf((funkey(k) - dmax) * INV_T);
      atomicAdd(&den_s, wgt);
      atomicAdd(&cls[labels[gi] & 15], wgt);
    }
  }
  __syncthreads();
  if (tid < N_CLASSES)
    out[(size_t)(row0 + row) * N_CLASSES + tid] = fminf(cls[tid] / den_s + 1e-5f, 1.0f);
}

// ---- host -------------------------------------------------------------------
extern "C" void kernel_launch(void* const* d_in, const int* in_sizes, int n_in,
                              void* d_out, int out_size, void* d_ws, size_t ws_size,
                              hipStream_t stream) {
  const float* x = (const float*)d_in[0];
  const float* mem = (const float*)d_in[1];
  const int* lbl = (const int*)d_in[2];
  float* out = (float*)d_out;

  char* w = (char*)d_ws;
  u16* mem_hi = (u16*)w;  w += (size_t)Q_N * D_DIM * 2;
  u16* mem_lo = (u16*)w;  w += (size_t)Q_N * D_DIM * 2;
  u16* x_hi = (u16*)w;    w += (size_t)B_ROWS * D_DIM * 2;
  u16* x_lo = (u16*)w;    w += (size_t)B_ROWS * D_DIM * 2;
  float* dist = (float*)w;

  size_t used = (size_t)(w - (char*)d_ws);
  size_t avail = ws_size > used ? ws_size - used : 0;
  int cr = (int)(avail / ((size_t)Q_N * 4));
  if (cr > 512) cr = 512;
  if (cr >= 64) cr &= ~63;
  if (cr < 1) cr = 1;

  xnorm_k<<<B_ROWS, 256, 0, stream>>>(x, x_hi, x_lo);
  mdecomp_k<<<2048, 256, 0, stream>>>((const float4*)mem, (ushort4*)mem_hi, (ushort4*)mem_lo,
                                      Q_N * D_DIM / 4);

  for (int r0 = 0; r0 < B_ROWS; r0 += cr) {
    int rows = min(cr, B_ROWS - r0);
    int mt = (rows + 127) / 128;
    int nwg = mt * (Q_N / 128);  // multiple of 8 (Q_N/128 = 512)
    gemm3_k<<<nwg, 256, 0, stream>>>(x_hi, x_lo, mem_hi, mem_lo, dist, r0, rows, mt, nwg);
    topk_k<<<rows, 1024, 0, stream>>>(dist, lbl, out, r0);
  }
}

// Round 4
// 620.431 us; speedup vs baseline: 2.9596x; 2.9596x over previous
//
#include <hip/hip_runtime.h>
#include <hip/hip_bf16.h>

#define B_ROWS 1024
#define D_DIM 256
#define Q_N 65536
#define K_TOP 200
#define N_CLASSES 10
#define INV_T 14.2857142857142857f /* 1/0.07 */
#define NCOLS_S 4096               /* sample columns for thresholding */
#define ST_SAMP 48u                /* sample-count target: E[true] = 16*48 = 768 */

typedef unsigned int u32;
typedef unsigned short u16;
typedef unsigned long long u64;

using bf16x8 = __attribute__((ext_vector_type(8))) __bf16;
using f32x4  = __attribute__((ext_vector_type(4))) float;

// ---- helpers ----------------------------------------------------------------

// order-preserving float->uint key (descending float == descending key)
__device__ __forceinline__ u32 fkey(float f) {
  u32 u = __float_as_uint(f);
  return (u >> 31) ? ~u : (u | 0x80000000u);
}
__device__ __forceinline__ float funkey(u32 u) {
  return __uint_as_float((u >> 31) ? (u & 0x7fffffffu) : ~u);
}
__device__ __forceinline__ u16 bf16_rn(float f) {
  u32 u = __float_as_uint(f);
  u32 r = (u + 0x7fffu + ((u >> 16) & 1u)) >> 16;
  return (u16)r;
}
// f ~= hi + lo with hi,lo bf16 (error ~2^-16 relative)
__device__ __forceinline__ void split2(float f, u16& h, u16& l) {
  u16 hh = bf16_rn(f);
  float hf = __uint_as_float(((u32)hh) << 16);
  h = hh;
  l = bf16_rn(f - hf);
}

__device__ __forceinline__ void gl16(const void* g, void* l) {
  __builtin_amdgcn_global_load_lds((const __attribute__((address_space(1))) u32*)g,
                                   (__attribute__((address_space(3))) u32*)l, 16, 0, 0);
}

// ---- kernel 1: x row-normalize + bf16 hi/lo split ---------------------------
__global__ __launch_bounds__(256) void xnorm_k(const float* __restrict__ x,
                                               u16* __restrict__ xh, u16* __restrict__ xl) {
  int row = blockIdx.x, t = threadIdx.x;
  int lane = t & 63, w = t >> 6;
  float v = x[row * D_DIM + t];
  float s = v * v;
  for (int o = 32; o > 0; o >>= 1) s += __shfl_down(s, o);
  __shared__ float ws[4];
  if (lane == 0) ws[w] = s;
  __syncthreads();
  if (t == 0) ws[0] = ws[0] + ws[1] + ws[2] + ws[3];
  __syncthreads();
  float inv = 1.0f / fmaxf(sqrtf(ws[0]), 1e-12f);
  u16 h, l;
  split2(v * inv, h, l);
  xh[row * D_DIM + t] = h;
  xl[row * D_DIM + t] = l;
}

// ---- kernel 2: memory bf16 hi/lo split --------------------------------------
__global__ __launch_bounds__(256) void mdecomp_k(const float4* __restrict__ m,
                                                 ushort4* __restrict__ mh,
                                                 ushort4* __restrict__ ml, int n4) {
  int i = blockIdx.x * blockDim.x + threadIdx.x;
  int stride = gridDim.x * blockDim.x;
  for (; i < n4; i += stride) {
    float4 v = m[i];
    ushort4 h, l;
    split2(v.x, h.x, l.x);
    split2(v.y, h.y, l.y);
    split2(v.z, h.z, l.z);
    split2(v.w, h.w, l.w);
    mh[i] = h;
    ml[i] = l;
  }
}

// ---- shared GEMM tile body: 128x128, BK=32, bf16x3 MFMA ---------------------
// LDS chunk-XOR bank swizzle applied via permuted GLOBAL source (linear LDS
// dest per global_load_lds contract) + matching ds_read offset swizzle.
__device__ __forceinline__ void gemm_tile(const u16* __restrict__ Ah, const u16* __restrict__ Al,
                                          const u16* __restrict__ Bh, const u16* __restrict__ Bl,
                                          int trow0, int col0, int tid, f32x4 (&acc)[4][4]) {
  __shared__ u16 sAh[4096], sAl[4096], sBh[4096], sBl[4096];  // 4 x 8KB
  int lane = tid & 63, wid = tid >> 6;
  int wr = wid >> 1, wc = wid & 1;

  int r_s = wid * 32 + (lane >> 2);
  int c_s = (((lane & 3) ^ ((lane >> 3) & 3)) << 3);
  int ar0 = trow0 + r_s, ar1 = ar0 + 16;   // trow0<=896, r_s<=111 -> in bounds
  int br0 = col0 + r_s, br1 = br0 + 16;

  int fr = lane & 15, fq = lane >> 4;
  int cswz = (fq ^ ((fr >> 1) & 3)) * 8;
  int a_off0 = (wr * 64 + fr) * 32 + cswz;
  int b_off0 = (wc * 64 + fr) * 32 + cswz;

  for (int kt = 0; kt < 8; ++kt) {
    int k0 = kt * 32;
    gl16(Ah + (size_t)ar0 * D_DIM + k0 + c_s, &sAh[wid * 1024]);
    gl16(Ah + (size_t)ar1 * D_DIM + k0 + c_s, &sAh[wid * 1024 + 512]);
    gl16(Al + (size_t)ar0 * D_DIM + k0 + c_s, &sAl[wid * 1024]);
    gl16(Al + (size_t)ar1 * D_DIM + k0 + c_s, &sAl[wid * 1024 + 512]);
    gl16(Bh + (size_t)br0 * D_DIM + k0 + c_s, &sBh[wid * 1024]);
    gl16(Bh + (size_t)br1 * D_DIM + k0 + c_s, &sBh[wid * 1024 + 512]);
    gl16(Bl + (size_t)br0 * D_DIM + k0 + c_s, &sBl[wid * 1024]);
    gl16(Bl + (size_t)br1 * D_DIM + k0 + c_s, &sBl[wid * 1024 + 512]);
    __syncthreads();

    bf16x8 ah[4], al[4], bh[4], bl[4];
#pragma unroll
    for (int m = 0; m < 4; ++m) {
      ah[m] = *(const bf16x8*)&sAh[a_off0 + m * 512];
      al[m] = *(const bf16x8*)&sAl[a_off0 + m * 512];
    }
#pragma unroll
    for (int n = 0; n < 4; ++n) {
      bh[n] = *(const bf16x8*)&sBh[b_off0 + n * 512];
      bl[n] = *(const bf16x8*)&sBl[b_off0 + n * 512];
    }
#pragma unroll
    for (int m = 0; m < 4; ++m)
#pragma unroll
      for (int n = 0; n < 4; ++n) {
        acc[m][n] = __builtin_amdgcn_mfma_f32_16x16x32_bf16(ah[m], bh[n], acc[m][n], 0, 0, 0);
        acc[m][n] = __builtin_amdgcn_mfma_f32_16x16x32_bf16(ah[m], bl[n], acc[m][n], 0, 0, 0);
        acc[m][n] = __builtin_amdgcn_mfma_f32_16x16x32_bf16(al[m], bh[n], acc[m][n], 0, 0, 0);
      }
    __syncthreads();
  }
}

// ---- kernel 3a: sample GEMM (cols 0..4095) -> dist_s ------------------------
__global__ __launch_bounds__(256) void gemm_s_k(const u16* __restrict__ Ah, const u16* __restrict__ Al,
                                                const u16* __restrict__ Bh, const u16* __restrict__ Bl,
                                                float* __restrict__ dist_s) {
  int tid = threadIdx.x;
  int trow0 = blockIdx.x << 7, col0 = blockIdx.y << 7;
  f32x4 acc[4][4] = {};
  gemm_tile(Ah, Al, Bh, Bl, trow0, col0, tid, acc);
  int lane = tid & 63, wid = tid >> 6;
  int wr = wid >> 1, wc = wid & 1, fr = lane & 15, fq = lane >> 4;
#pragma unroll
  for (int m = 0; m < 4; ++m) {
    int rr = trow0 + wr * 64 + m * 16 + fq * 4;
#pragma unroll
    for (int n = 0; n < 4; ++n) {
      int cc = col0 + wc * 64 + n * 16 + fr;
#pragma unroll
      for (int r = 0; r < 4; ++r)
        dist_s[(size_t)(rr + r) * NCOLS_S + cc] = acc[m][n][r];
    }
  }
}

// ---- kernel 3b: per-row coarse threshold from sample ------------------------
__global__ __launch_bounds__(256) void thr_k(const float* __restrict__ dist_s,
                                             u32* __restrict__ tkeyA, u32* __restrict__ cnt) {
  __shared__ u32 shist[1024];
  __shared__ u32 wtot[4];
  int row = blockIdx.x, tid = threadIdx.x, lane = tid & 63, w = tid >> 6;
  const float4* dp = (const float4*)(dist_s + (size_t)row * NCOLS_S);
  shist[tid] = 0; shist[tid + 256] = 0; shist[tid + 512] = 0; shist[tid + 768] = 0;
  __syncthreads();
#pragma unroll
  for (int j = 0; j < 4; ++j) {
    float4 v = dp[tid + (j << 8)];
    atomicAdd(&shist[fkey(v.x) >> 22], 1u);
    atomicAdd(&shist[fkey(v.y) >> 22], 1u);
    atomicAdd(&shist[fkey(v.z) >> 22], 1u);
    atomicAdd(&shist[fkey(v.w) >> 22], 1u);
  }
  __syncthreads();
  u32 cs = shist[tid * 4] + shist[tid * 4 + 1] + shist[tid * 4 + 2] + shist[tid * 4 + 3];
  u32 sfx = cs;
#pragma unroll
  for (int off = 1; off < 64; off <<= 1) {
    u32 t = __shfl_down(sfx, off);
    sfx += (lane + off < 64) ? t : 0u;
  }
  if (lane == 0) wtot[w] = sfx;
  __syncthreads();
  u32 woff = 0;
  for (int j = w + 1; j < 4; ++j) woff += wtot[j];
  u32 S = sfx + woff, Safter = S - cs;
  if (S >= ST_SAMP && Safter < ST_SAMP) {  // unique crossing chunk
    u32 cum = Safter;
    int bin = tid * 4;
    for (int b = tid * 4 + 3; b >= tid * 4; --b) {
      u32 hb = shist[b];
      if (cum + hb >= ST_SAMP) { bin = b; break; }
      cum += hb;
    }
    tkeyA[row] = ((u32)bin) << 22;
  }
  if (tid == 0) cnt[row] = 0;
}

// ---- kernel 4: main GEMM with filtering epilogue (no dist materialized) -----
// 1D grid of 4096, XCD-chunked swizzle with row-tile fastest: all 8 row-tiles
// of a B col-tile land on the same XCD -> B read once per XCD L2.
__global__ __launch_bounds__(256) void gemm_f_k(const u16* __restrict__ Ah, const u16* __restrict__ Al,
                                                const u16* __restrict__ Bh, const u16* __restrict__ Bl,
                                                const u32* __restrict__ tkeyA, u32* __restrict__ cnt,
                                                u64* __restrict__ cand, int cap) {
  __shared__ u32 sT[128];
  int tid = threadIdx.x;
  int bid = blockIdx.x;
  int swz = (bid & 7) * 512 + (bid >> 3);
  int trow0 = (swz & 7) << 7;   // row tile fastest
  int col0 = (swz >> 3) << 7;
  if (tid < 128) sT[tid] = tkeyA[trow0 + tid];
  f32x4 acc[4][4] = {};
  gemm_tile(Ah, Al, Bh, Bl, trow0, col0, tid, acc);
  int lane = tid & 63, wid = tid >> 6;
  int wr = wid >> 1, wc = wid & 1, fr = lane & 15, fq = lane >> 4;
#pragma unroll
  for (int m = 0; m < 4; ++m) {
    int lr0 = wr * 64 + m * 16 + fq * 4;
#pragma unroll
    for (int n = 0; n < 4; ++n) {
      int cc = col0 + wc * 64 + n * 16 + fr;
#pragma unroll
      for (int r = 0; r < 4; ++r) {
        u32 k = fkey(acc[m][n][r]);
        if (k >= sT[lr0 + r]) {
          int grow = trow0 + lr0 + r;
          u32 slot = atomicAdd(&cnt[grow], 1u);
          if (slot < (u32)cap)
            cand[(size_t)grow * cap + slot] = ((u64)k << 32) | (u32)(~(u32)cc);
        }
      }
    }
  }
}

// ---- kernel 5: per-row finish: fine hist + boundary rank + class scores -----
__global__ __launch_bounds__(1024) void topk2_k(const u64* __restrict__ cand, const u32* __restrict__ cnt,
                                                const u32* __restrict__ tkeyA, const int* __restrict__ labels,
                                                float* __restrict__ out, int cap) {
  __shared__ u32 fhist[2048];  // 8 KB
  __shared__ u32 shist[1024];  // 4 KB
  __shared__ u32 wtot[16];
  __shared__ u64 bnd[2048];    // 16 KB boundary-bin members
  __shared__ float cls[16];
  __shared__ float den_s;
  __shared__ u32 bcnt_s, bstar_s, cab_s;
  __shared__ u64 maxp_s;
  int row = blockIdx.x, tid = threadIdx.x, lane = tid & 63, w = tid >> 6;
  u32 c = cnt[row];
  if (c > (u32)cap) c = (u32)cap;
  u32 tkey = tkeyA[row];
  const u64* cp = cand + (size_t)row * cap;

  fhist[tid] = 0; fhist[tid + 1024] = 0;
  if (tid < 16) cls[tid] = 0.f;
  if (tid == 0) { den_s = 0.f; bcnt_s = 0; bstar_s = 0; cab_s = 0; maxp_s = 0; }
  __syncthreads();

  // pass A: max + fine histogram (bin = (key - tkey) >> 14, clamped)
  u64 mp = 0;
  for (u32 i = tid; i < c; i += 1024) {
    u64 p = cp[i];
    mp = p > mp ? p : mp;
    u32 fb = ((u32)(p >> 32) - tkey) >> 14;
    if (fb > 2047u) fb = 2047u;
    atomicAdd(&fhist[fb], 1u);
  }
#pragma unroll
  for (int off = 32; off > 0; off >>= 1) {
    u64 t = __shfl_down(mp, off);
    mp = t > mp ? t : mp;
  }
  if (lane == 0) atomicMax((unsigned long long*)&maxp_s, (unsigned long long)mp);
  __syncthreads();
  float dmax = funkey((u32)(maxp_s >> 32));
  bool allin = (c <= K_TOP);

  if (!allin) {  // suffix-scan 2-bin chunks -> boundary bin b*, count_above
    u32 cs2 = fhist[2 * tid] + fhist[2 * tid + 1];
    u32 sfx = cs2;
#pragma unroll
    for (int off = 1; off < 64; off <<= 1) {
      u32 t = __shfl_down(sfx, off);
      sfx += (lane + off < 64) ? t : 0u;
    }
    if (lane == 0) wtot[w] = sfx;
    __syncthreads();
    u32 woff = 0;
    for (int j = w + 1; j < 16; ++j) woff += wtot[j];
    u32 S = sfx + woff, Safter = S - cs2;
    if (S >= K_TOP && Safter < K_TOP) {
      u32 cum = Safter;
      int bs = 2 * tid;
      u32 cabv = 0;
      for (int b = 2 * tid + 1; b >= 2 * tid; --b) {
        u32 hb = fhist[b];
        if (cum + hb >= K_TOP) { bs = b; cabv = cum; break; }
        cum += hb;
      }
      bstar_s = (u32)bs;
      cab_s = cabv;
    }
    __syncthreads();
  }
  u32 bstar = bstar_s;
  int Kp = K_TOP - (int)cab_s;

  // pass B: definite items accumulate; boundary-bin members -> LDS
  for (u32 i = tid; i < c; i += 1024) {
    u64 p = cp[i];
    u32 k = (u32)(p >> 32);
    u32 fb = (k - tkey) >> 14;
    if (fb > 2047u) fb = 2047u;
    if (allin || fb > bstar) {
      float wgt = __expf((funkey(k) - dmax) * INV_T);
      atomicAdd(&den_s, wgt);
      u32 col = ~(u32)(p & 0xffffffffu);
      atomicAdd(&cls[labels[col & 0xffff] & 15], wgt);
    } else if (fb == bstar) {
      u32 s2 = atomicAdd(&bcnt_s, 1u);
      if (s2 < 2048u) bnd[s2] = p;
    }
  }
  __syncthreads();
  if (!allin) {  // exact rank within boundary bin (packed compare: ties by idx)
    int bc = (int)min(bcnt_s, 2048u);
    for (int i = tid; i < bc; i += 1024) {
      u64 p = bnd[i];
      int r = 0;
      for (int j = 0; j < bc; ++j) r += (bnd[j] > p) ? 1 : 0;
      if (r < Kp) {
        u32 k = (u32)(p >> 32);
        float wgt = __expf((funkey(k) - dmax) * INV_T);
        atomicAdd(&den_s, wgt);
        u32 col = ~(u32)(p & 0xffffffffu);
        atomicAdd(&cls[labels[col & 0xffff] & 15], wgt);
      }
    }
    __syncthreads();
  }
  if (tid < N_CLASSES)
    out[(size_t)row * N_CLASSES + tid] = fminf(cls[tid] / den_s + 1e-5f, 1.0f);
}

// ---- host -------------------------------------------------------------------
extern "C" void kernel_launch(void* const* d_in, const int* in_sizes, int n_in,
                              void* d_out, int out_size, void* d_ws, size_t ws_size,
                              hipStream_t stream) {
  const float* x = (const float*)d_in[0];
  const float* mem = (const float*)d_in[1];
  const int* lbl = (const int*)d_in[2];
  float* out = (float*)d_out;

  char* w = (char*)d_ws;
  u16* mem_hi = (u16*)w;  w += (size_t)Q_N * D_DIM * 2;
  u16* mem_lo = (u16*)w;  w += (size_t)Q_N * D_DIM * 2;
  u16* x_hi = (u16*)w;    w += (size_t)B_ROWS * D_DIM * 2;
  u16* x_lo = (u16*)w;    w += (size_t)B_ROWS * D_DIM * 2;
  u32* tkeyA = (u32*)w;   w += (size_t)B_ROWS * 4;
  u32* cntA = (u32*)w;    w += (size_t)B_ROWS * 4;
  float* dist_s = (float*)w;  w += (size_t)B_ROWS * NCOLS_S * 4;
  u64* cand = (u64*)w;

  size_t used = (size_t)(w - (char*)d_ws);
  size_t avail = ws_size > used ? ws_size - used : 0;
  int cap = (int)(avail / ((size_t)B_ROWS * 8));
  if (cap > 12288) cap = 12288;
  if (cap < 1024) cap = 1024;  // statistically never needed below this

  xnorm_k<<<B_ROWS, 256, 0, stream>>>(x, x_hi, x_lo);
  mdecomp_k<<<2048, 256, 0, stream>>>((const float4*)mem, (ushort4*)mem_hi, (ushort4*)mem_lo,
                                      Q_N * D_DIM / 4);
  gemm_s_k<<<dim3(8, 32), 256, 0, stream>>>(x_hi, x_lo, mem_hi, mem_lo, dist_s);
  thr_k<<<B_ROWS, 256, 0, stream>>>(dist_s, tkeyA, cntA);
  gemm_f_k<<<4096, 256, 0, stream>>>(x_hi, x_lo, mem_hi, mem_lo, tkeyA, cntA, cand, cap);
  topk2_k<<<B_ROWS, 1024, 0, stream>>>(cand, cntA, tkeyA, lbl, out, cap);
}

// Round 5
// 314.058 us; speedup vs baseline: 5.8468x; 1.9755x over previous
//
#include <hip/hip_runtime.h>
#include <hip/hip_bf16.h>

#define B_ROWS 1024
#define D_DIM 256
#define Q_N 65536
#define K_TOP 200
#define N_CLASSES 10
#define INV_T 14.2857142857142857f /* 1/0.07 */
#define NCOLS_S 4096               /* sample columns for thresholding */
#define ST_SAMP 48u                /* sample-count target: E[true] = 16*48 = 768 */
#define SCAP 4096                  /* per-block LDS survivor capacity */

typedef unsigned int u32;
typedef unsigned short u16;
typedef unsigned long long u64;

using bf16x8 = __attribute__((ext_vector_type(8))) __bf16;
using f32x4  = __attribute__((ext_vector_type(4))) float;

// ---- helpers ----------------------------------------------------------------

// order-preserving float->uint key (descending float == descending key)
__device__ __forceinline__ u32 fkey(float f) {
  u32 u = __float_as_uint(f);
  return (u >> 31) ? ~u : (u | 0x80000000u);
}
__device__ __forceinline__ float funkey(u32 u) {
  return __uint_as_float((u >> 31) ? (u & 0x7fffffffu) : ~u);
}
__device__ __forceinline__ u16 bf16_rn(float f) {
  u32 u = __float_as_uint(f);
  u32 r = (u + 0x7fffu + ((u >> 16) & 1u)) >> 16;
  return (u16)r;
}
// f ~= hi + lo with hi,lo bf16 (error ~2^-16 relative)
__device__ __forceinline__ void split2(float f, u16& h, u16& l) {
  u16 hh = bf16_rn(f);
  float hf = __uint_as_float(((u32)hh) << 16);
  h = hh;
  l = bf16_rn(f - hf);
}

__device__ __forceinline__ void gl16(const void* g, void* l) {
  __builtin_amdgcn_global_load_lds((const __attribute__((address_space(1))) u32*)g,
                                   (__attribute__((address_space(3))) u32*)l, 16, 0, 0);
}

// ---- kernel 1: x row-normalize + bf16 hi/lo split ---------------------------
__global__ __launch_bounds__(256) void xnorm_k(const float* __restrict__ x,
                                               u16* __restrict__ xh, u16* __restrict__ xl) {
  int row = blockIdx.x, t = threadIdx.x;
  int lane = t & 63, w = t >> 6;
  float v = x[row * D_DIM + t];
  float s = v * v;
  for (int o = 32; o > 0; o >>= 1) s += __shfl_down(s, o);
  __shared__ float ws[4];
  if (lane == 0) ws[w] = s;
  __syncthreads();
  if (t == 0) ws[0] = ws[0] + ws[1] + ws[2] + ws[3];
  __syncthreads();
  float inv = 1.0f / fmaxf(sqrtf(ws[0]), 1e-12f);
  u16 h, l;
  split2(v * inv, h, l);
  xh[row * D_DIM + t] = h;
  xl[row * D_DIM + t] = l;
}

// ---- kernel 2: memory bf16 hi/lo split --------------------------------------
__global__ __launch_bounds__(256) void mdecomp_k(const float4* __restrict__ m,
                                                 ushort4* __restrict__ mh,
                                                 ushort4* __restrict__ ml, int n4) {
  int i = blockIdx.x * blockDim.x + threadIdx.x;
  int stride = gridDim.x * blockDim.x;
  for (; i < n4; i += stride) {
    float4 v = m[i];
    ushort4 h, l;
    split2(v.x, h.x, l.x);
    split2(v.y, h.y, l.y);
    split2(v.z, h.z, l.z);
    split2(v.w, h.w, l.w);
    mh[i] = h;
    ml[i] = l;
  }
}

// ---- shared GEMM tile body: 128x128, BK=32, bf16x3 MFMA ---------------------
// sm: 16384 u16 (32 KB) staging buffer, dead after return (reusable).
// LDS chunk-XOR bank swizzle applied via permuted GLOBAL source (linear LDS
// dest per global_load_lds contract) + matching ds_read offset swizzle.
__device__ __forceinline__ void gemm_tile(const u16* __restrict__ Ah, const u16* __restrict__ Al,
                                          const u16* __restrict__ Bh, const u16* __restrict__ Bl,
                                          int trow0, int col0, int tid, u16* sm, f32x4 (&acc)[4][4]) {
  u16* sAh = sm;
  u16* sAl = sm + 4096;
  u16* sBh = sm + 8192;
  u16* sBl = sm + 12288;
  int lane = tid & 63, wid = tid >> 6;
  int wr = wid >> 1, wc = wid & 1;

  int r_s = wid * 32 + (lane >> 2);
  int c_s = (((lane & 3) ^ ((lane >> 3) & 3)) << 3);
  int ar0 = trow0 + r_s, ar1 = ar0 + 16;   // trow0<=896, r_s<=111 -> in bounds
  int br0 = col0 + r_s, br1 = br0 + 16;

  int fr = lane & 15, fq = lane >> 4;
  int cswz = (fq ^ ((fr >> 1) & 3)) * 8;
  int a_off0 = (wr * 64 + fr) * 32 + cswz;
  int b_off0 = (wc * 64 + fr) * 32 + cswz;

  for (int kt = 0; kt < 8; ++kt) {
    int k0 = kt * 32;
    gl16(Ah + (size_t)ar0 * D_DIM + k0 + c_s, &sAh[wid * 1024]);
    gl16(Ah + (size_t)ar1 * D_DIM + k0 + c_s, &sAh[wid * 1024 + 512]);
    gl16(Al + (size_t)ar0 * D_DIM + k0 + c_s, &sAl[wid * 1024]);
    gl16(Al + (size_t)ar1 * D_DIM + k0 + c_s, &sAl[wid * 1024 + 512]);
    gl16(Bh + (size_t)br0 * D_DIM + k0 + c_s, &sBh[wid * 1024]);
    gl16(Bh + (size_t)br1 * D_DIM + k0 + c_s, &sBh[wid * 1024 + 512]);
    gl16(Bl + (size_t)br0 * D_DIM + k0 + c_s, &sBl[wid * 1024]);
    gl16(Bl + (size_t)br1 * D_DIM + k0 + c_s, &sBl[wid * 1024 + 512]);
    __syncthreads();

    bf16x8 ah[4], al[4], bh[4], bl[4];
#pragma unroll
    for (int m = 0; m < 4; ++m) {
      ah[m] = *(const bf16x8*)&sAh[a_off0 + m * 512];
      al[m] = *(const bf16x8*)&sAl[a_off0 + m * 512];
    }
#pragma unroll
    for (int n = 0; n < 4; ++n) {
      bh[n] = *(const bf16x8*)&sBh[b_off0 + n * 512];
      bl[n] = *(const bf16x8*)&sBl[b_off0 + n * 512];
    }
#pragma unroll
    for (int m = 0; m < 4; ++m)
#pragma unroll
      for (int n = 0; n < 4; ++n) {
        acc[m][n] = __builtin_amdgcn_mfma_f32_16x16x32_bf16(ah[m], bh[n], acc[m][n], 0, 0, 0);
        acc[m][n] = __builtin_amdgcn_mfma_f32_16x16x32_bf16(ah[m], bl[n], acc[m][n], 0, 0, 0);
        acc[m][n] = __builtin_amdgcn_mfma_f32_16x16x32_bf16(al[m], bh[n], acc[m][n], 0, 0, 0);
      }
    __syncthreads();
  }
}

// ---- kernel 3a: sample GEMM (cols 0..4095) -> dist_s ------------------------
__global__ __launch_bounds__(256) void gemm_s_k(const u16* __restrict__ Ah, const u16* __restrict__ Al,
                                                const u16* __restrict__ Bh, const u16* __restrict__ Bl,
                                                float* __restrict__ dist_s) {
  __shared__ u16 sm[16384];
  int tid = threadIdx.x;
  int trow0 = blockIdx.x << 7, col0 = blockIdx.y << 7;
  f32x4 acc[4][4] = {};
  gemm_tile(Ah, Al, Bh, Bl, trow0, col0, tid, sm, acc);
  int lane = tid & 63, wid = tid >> 6;
  int wr = wid >> 1, wc = wid & 1, fr = lane & 15, fq = lane >> 4;
#pragma unroll
  for (int m = 0; m < 4; ++m) {
    int rr = trow0 + wr * 64 + m * 16 + fq * 4;
#pragma unroll
    for (int n = 0; n < 4; ++n) {
      int cc = col0 + wc * 64 + n * 16 + fr;
#pragma unroll
      for (int r = 0; r < 4; ++r)
        dist_s[(size_t)(rr + r) * NCOLS_S + cc] = acc[m][n][r];
    }
  }
}

// ---- kernel 3b: per-row coarse threshold from sample ------------------------
__global__ __launch_bounds__(256) void thr_k(const float* __restrict__ dist_s,
                                             u32* __restrict__ tkeyA, u32* __restrict__ cnt) {
  __shared__ u32 shist[1024];
  __shared__ u32 wtot[4];
  int row = blockIdx.x, tid = threadIdx.x, lane = tid & 63, w = tid >> 6;
  const float4* dp = (const float4*)(dist_s + (size_t)row * NCOLS_S);
  shist[tid] = 0; shist[tid + 256] = 0; shist[tid + 512] = 0; shist[tid + 768] = 0;
  __syncthreads();
#pragma unroll
  for (int j = 0; j < 4; ++j) {
    float4 v = dp[tid + (j << 8)];
    atomicAdd(&shist[fkey(v.x) >> 22], 1u);
    atomicAdd(&shist[fkey(v.y) >> 22], 1u);
    atomicAdd(&shist[fkey(v.z) >> 22], 1u);
    atomicAdd(&shist[fkey(v.w) >> 22], 1u);
  }
  __syncthreads();
  u32 cs = shist[tid * 4] + shist[tid * 4 + 1] + shist[tid * 4 + 2] + shist[tid * 4 + 3];
  u32 sfx = cs;
#pragma unroll
  for (int off = 1; off < 64; off <<= 1) {
    u32 t = __shfl_down(sfx, off);
    sfx += (lane + off < 64) ? t : 0u;
  }
  if (lane == 0) wtot[w] = sfx;
  __syncthreads();
  u32 woff = 0;
  for (int j = w + 1; j < 4; ++j) woff += wtot[j];
  u32 S = sfx + woff, Safter = S - cs;
  if (S >= ST_SAMP && Safter < ST_SAMP) {  // unique crossing chunk
    u32 cum = Safter;
    int bin = tid * 4;
    for (int b = tid * 4 + 3; b >= tid * 4; --b) {
      u32 hb = shist[b];
      if (cum + hb >= ST_SAMP) { bin = b; break; }
      cum += hb;
    }
    tkeyA[row] = ((u32)bin) << 22;
  }
  if (tid == 0) cnt[row] = 0;
}

// ---- kernel 4: main GEMM with filtering epilogue (no dist materialized) -----
// Survivors staged in LDS (reusing the dead GEMM staging buffer), flushed with
// ONE global atomicAdd per (row, block) by 128 parallel threads — no per-wave
// serialized atomic round-trips (round-4's 500us stall).
__global__ __launch_bounds__(256) void gemm_f_k(const u16* __restrict__ Ah, const u16* __restrict__ Al,
                                                const u16* __restrict__ Bh, const u16* __restrict__ Bl,
                                                const u32* __restrict__ tkeyA, u32* __restrict__ cnt,
                                                u64* __restrict__ cand, int cap) {
  __shared__ u16 sm[16384];   // GEMM staging; aliased as u64 sbuf[4096] in epilogue
  __shared__ u32 sT[128];
  __shared__ u32 rcnt[128], rbase[128], rcur[128];
  __shared__ u32 scnt;
  int tid = threadIdx.x;
  int bid = blockIdx.x;
  int swz = (bid & 7) * 512 + (bid >> 3);
  int trow0 = (swz & 7) << 7;   // row tile fastest: 8 row-tiles/col-tile on one XCD
  int col0 = (swz >> 3) << 7;
  if (tid < 128) { sT[tid] = tkeyA[trow0 + tid]; rcnt[tid] = 0; }
  if (tid == 0) scnt = 0;
  // (visibility of the above guaranteed by gemm_tile's internal barriers)
  f32x4 acc[4][4] = {};
  gemm_tile(Ah, Al, Bh, Bl, trow0, col0, tid, sm, acc);

  u64* sbuf = (u64*)sm;  // staging dead after gemm_tile's final barrier
  int lane = tid & 63, wid = tid >> 6;
  int wr = wid >> 1, wc = wid & 1, fr = lane & 15, fq = lane >> 4;
#pragma unroll
  for (int m = 0; m < 4; ++m) {
    int lr0 = wr * 64 + m * 16 + fq * 4;
#pragma unroll
    for (int n = 0; n < 4; ++n) {
      int cc = col0 + wc * 64 + n * 16 + fr;
#pragma unroll
      for (int r = 0; r < 4; ++r) {
        u32 k = fkey(acc[m][n][r]);
        int lrow = lr0 + r;
        if (k >= sT[lrow]) {
          u32 s = atomicAdd(&scnt, 1u);
          if (s < (u32)SCAP) {  // LDS fast path (always, statistically)
            sbuf[s] = ((u64)k << 32) | ((u64)(u32)lrow << 16) | (u64)(u32)cc;
            atomicAdd(&rcnt[lrow], 1u);
          } else {              // overflow fallback: direct global
            int grow = trow0 + lrow;
            u32 s2 = atomicAdd(&cnt[grow], 1u);
            if (s2 < (u32)cap) cand[(size_t)grow * cap + s2] = ((u64)k << 32) | (u32)(~(u32)cc);
          }
        }
      }
    }
  }
  __syncthreads();
  if (tid < 128) {  // one global atomic per row, 128 in parallel
    u32 nr = rcnt[tid];
    rbase[tid] = nr ? atomicAdd(&cnt[trow0 + tid], nr) : 0u;
    rcur[tid] = 0;
  }
  __syncthreads();
  u32 total = min(scnt, (u32)SCAP);
  for (u32 i = tid; i < total; i += 256) {
    u64 e = sbuf[i];
    u32 lrow = (u32)(e >> 16) & 127u;
    u32 col = (u32)e & 0xffffu;
    u32 key = (u32)(e >> 32);
    u32 off = atomicAdd(&rcur[lrow], 1u);   // LDS
    u32 slot = rbase[lrow] + off;
    if (slot < (u32)cap)
      cand[(size_t)(trow0 + lrow) * cap + slot] = ((u64)key << 32) | (u32)(~col);
  }
}

// ---- kernel 5: per-row finish: fine hist + boundary rank + class scores -----
__global__ __launch_bounds__(1024) void topk2_k(const u64* __restrict__ cand, const u32* __restrict__ cnt,
                                                const u32* __restrict__ tkeyA, const int* __restrict__ labels,
                                                float* __restrict__ out, int cap) {
  __shared__ u32 fhist[2048];  // 8 KB
  __shared__ u32 wtot[16];
  __shared__ u64 bnd[2048];    // 16 KB boundary-bin members
  __shared__ float cls[16];
  __shared__ float den_s;
  __shared__ u32 bcnt_s, bstar_s, cab_s;
  __shared__ u64 maxp_s;
  int row = blockIdx.x, tid = threadIdx.x, lane = tid & 63, w = tid >> 6;
  u32 c = cnt[row];
  if (c > (u32)cap) c = (u32)cap;
  u32 tkey = tkeyA[row];
  const u64* cp = cand + (size_t)row * cap;

  fhist[tid] = 0; fhist[tid + 1024] = 0;
  if (tid < 16) cls[tid] = 0.f;
  if (tid == 0) { den_s = 0.f; bcnt_s = 0; bstar_s = 0; cab_s = 0; maxp_s = 0; }
  __syncthreads();

  // pass A: max + fine histogram (bin = (key - tkey) >> 14, clamped)
  u64 mp = 0;
  for (u32 i = tid; i < c; i += 1024) {
    u64 p = cp[i];
    mp = p > mp ? p : mp;
    u32 fb = ((u32)(p >> 32) - tkey) >> 14;
    if (fb > 2047u) fb = 2047u;
    atomicAdd(&fhist[fb], 1u);
  }
#pragma unroll
  for (int off = 32; off > 0; off >>= 1) {
    u64 t = __shfl_down(mp, off);
    mp = t > mp ? t : mp;
  }
  if (lane == 0) atomicMax((unsigned long long*)&maxp_s, (unsigned long long)mp);
  __syncthreads();
  float dmax = funkey((u32)(maxp_s >> 32));
  bool allin = (c <= K_TOP);

  if (!allin) {  // suffix-scan 2-bin chunks -> boundary bin b*, count_above
    u32 cs2 = fhist[2 * tid] + fhist[2 * tid + 1];
    u32 sfx = cs2;
#pragma unroll
    for (int off = 1; off < 64; off <<= 1) {
      u32 t = __shfl_down(sfx, off);
      sfx += (lane + off < 64) ? t : 0u;
    }
    if (lane == 0) wtot[w] = sfx;
    __syncthreads();
    u32 woff = 0;
    for (int j = w + 1; j < 16; ++j) woff += wtot[j];
    u32 S = sfx + woff, Safter = S - cs2;
    if (S >= K_TOP && Safter < K_TOP) {
      u32 cum = Safter;
      int bs = 2 * tid;
      u32 cabv = 0;
      for (int b = 2 * tid + 1; b >= 2 * tid; --b) {
        u32 hb = fhist[b];
        if (cum + hb >= K_TOP) { bs = b; cabv = cum; break; }
        cum += hb;
      }
      bstar_s = (u32)bs;
      cab_s = cabv;
    }
    __syncthreads();
  }
  u32 bstar = bstar_s;
  int Kp = K_TOP - (int)cab_s;

  // pass B: definite items accumulate; boundary-bin members -> LDS
  for (u32 i = tid; i < c; i += 1024) {
    u64 p = cp[i];
    u32 k = (u32)(p >> 32);
    u32 fb = (k - tkey) >> 14;
    if (fb > 2047u) fb = 2047u;
    if (allin || fb > bstar) {
      float wgt = __expf((funkey(k) - dmax) * INV_T);
      atomicAdd(&den_s, wgt);
      u32 col = ~(u32)(p & 0xffffffffu);
      atomicAdd(&cls[labels[col & 0xffff] & 15], wgt);
    } else if (fb == bstar) {
      u32 s2 = atomicAdd(&bcnt_s, 1u);
      if (s2 < 2048u) bnd[s2] = p;
    }
  }
  __syncthreads();
  if (!allin) {  // exact rank within boundary bin (packed compare: ties by idx)
    int bc = (int)min(bcnt_s, 2048u);
    for (int i = tid; i < bc; i += 1024) {
      u64 p = bnd[i];
      int r = 0;
      for (int j = 0; j < bc; ++j) r += (bnd[j] > p) ? 1 : 0;
      if (r < Kp) {
        u32 k = (u32)(p >> 32);
        float wgt = __expf((funkey(k) - dmax) * INV_T);
        atomicAdd(&den_s, wgt);
        u32 col = ~(u32)(p & 0xffffffffu);
        atomicAdd(&cls[labels[col & 0xffff] & 15], wgt);
      }
    }
    __syncthreads();
  }
  if (tid < N_CLASSES)
    out[(size_t)row * N_CLASSES + tid] = fminf(cls[tid] / den_s + 1e-5f, 1.0f);
}

// ---- host -------------------------------------------------------------------
extern "C" void kernel_launch(void* const* d_in, const int* in_sizes, int n_in,
                              void* d_out, int out_size, void* d_ws, size_t ws_size,
                              hipStream_t stream) {
  const float* x = (const float*)d_in[0];
  const float* mem = (const float*)d_in[1];
  const int* lbl = (const int*)d_in[2];
  float* out = (float*)d_out;

  char* w = (char*)d_ws;
  u16* mem_hi = (u16*)w;  w += (size_t)Q_N * D_DIM * 2;
  u16* mem_lo = (u16*)w;  w += (size_t)Q_N * D_DIM * 2;
  u16* x_hi = (u16*)w;    w += (size_t)B_ROWS * D_DIM * 2;
  u16* x_lo = (u16*)w;    w += (size_t)B_ROWS * D_DIM * 2;
  u32* tkeyA = (u32*)w;   w += (size_t)B_ROWS * 4;
  u32* cntA = (u32*)w;    w += (size_t)B_ROWS * 4;
  float* dist_s = (float*)w;  w += (size_t)B_ROWS * NCOLS_S * 4;
  u64* cand = (u64*)w;

  size_t used = (size_t)(w - (char*)d_ws);
  size_t avail = ws_size > used ? ws_size - used : 0;
  int cap = (int)(avail / ((size_t)B_ROWS * 8));
  if (cap > 12288) cap = 12288;
  if (cap < 1024) cap = 1024;  // statistically never needed below this

  xnorm_k<<<B_ROWS, 256, 0, stream>>>(x, x_hi, x_lo);
  mdecomp_k<<<2048, 256, 0, stream>>>((const float4*)mem, (ushort4*)mem_hi, (ushort4*)mem_lo,
                                      Q_N * D_DIM / 4);
  gemm_s_k<<<dim3(8, 32), 256, 0, stream>>>(x_hi, x_lo, mem_hi, mem_lo, dist_s);
  thr_k<<<B_ROWS, 256, 0, stream>>>(dist_s, tkeyA, cntA);
  gemm_f_k<<<4096, 256, 0, stream>>>(x_hi, x_lo, mem_hi, mem_lo, tkeyA, cntA, cand, cap);
  topk2_k<<<B_ROWS, 1024, 0, stream>>>(cand, cntA, tkeyA, lbl, out, cap);
}

// Round 6
// 305.259 us; speedup vs baseline: 6.0153x; 1.0288x over previous
//
#include <hip/hip_runtime.h>
#include <hip/hip_bf16.h>

#define B_ROWS 1024
#define D_DIM 256
#define Q_N 65536
#define K_TOP 200
#define N_CLASSES 10
#define INV_T 14.2857142857142857f /* 1/0.07 */
#define NCOLS_S 4096               /* sample columns for thresholding */
#define ST_SAMP 48u                /* sample-count target: E[true] = 16*48 = 768 */
#define SCAP 4096                  /* per-block LDS survivor capacity */

typedef unsigned int u32;
typedef unsigned short u16;
typedef unsigned long long u64;

using bf16x8 = __attribute__((ext_vector_type(8))) __bf16;
using f32x4  = __attribute__((ext_vector_type(4))) float;

// ---- helpers ----------------------------------------------------------------

// order-preserving float->uint key (descending float == descending key)
__device__ __forceinline__ u32 fkey(float f) {
  u32 u = __float_as_uint(f);
  return (u >> 31) ? ~u : (u | 0x80000000u);
}
__device__ __forceinline__ float funkey(u32 u) {
  return __uint_as_float((u >> 31) ? (u & 0x7fffffffu) : ~u);
}
__device__ __forceinline__ u16 bf16_rn(float f) {
  u32 u = __float_as_uint(f);
  u32 r = (u + 0x7fffu + ((u >> 16) & 1u)) >> 16;
  return (u16)r;
}
// f ~= hi + lo with hi,lo bf16 (error ~2^-16 relative)
__device__ __forceinline__ void split2(float f, u16& h, u16& l) {
  u16 hh = bf16_rn(f);
  float hf = __uint_as_float(((u32)hh) << 16);
  h = hh;
  l = bf16_rn(f - hf);
}

__device__ __forceinline__ void gl16(const void* g, void* l) {
  __builtin_amdgcn_global_load_lds((const __attribute__((address_space(1))) u32*)g,
                                   (__attribute__((address_space(3))) u32*)l, 16, 0, 0);
}

// ---- kernel 1: x row-normalize + bf16 hi/lo split ---------------------------
__global__ __launch_bounds__(256) void xnorm_k(const float* __restrict__ x,
                                               u16* __restrict__ xh, u16* __restrict__ xl) {
  int row = blockIdx.x, t = threadIdx.x;
  int lane = t & 63, w = t >> 6;
  float v = x[row * D_DIM + t];
  float s = v * v;
  for (int o = 32; o > 0; o >>= 1) s += __shfl_down(s, o);
  __shared__ float ws[4];
  if (lane == 0) ws[w] = s;
  __syncthreads();
  if (t == 0) ws[0] = ws[0] + ws[1] + ws[2] + ws[3];
  __syncthreads();
  float inv = 1.0f / fmaxf(sqrtf(ws[0]), 1e-12f);
  u16 h, l;
  split2(v * inv, h, l);
  xh[row * D_DIM + t] = h;
  xl[row * D_DIM + t] = l;
}

// ---- kernel 2: memory bf16 hi/lo split --------------------------------------
__global__ __launch_bounds__(256) void mdecomp_k(const float4* __restrict__ m,
                                                 ushort4* __restrict__ mh,
                                                 ushort4* __restrict__ ml, int n4) {
  int i = blockIdx.x * blockDim.x + threadIdx.x;
  int stride = gridDim.x * blockDim.x;
  for (; i < n4; i += stride) {
    float4 v = m[i];
    ushort4 h, l;
    split2(v.x, h.x, l.x);
    split2(v.y, h.y, l.y);
    split2(v.z, h.z, l.z);
    split2(v.w, h.w, l.w);
    mh[i] = h;
    ml[i] = l;
  }
}

// ---- shared GEMM tile body: 128x128, BK=32, bf16x3 MFMA, DOUBLE-BUFFERED ----
// sm: 32768 u16 (64 KB) staging, dead after return (reusable).
// 2-phase schedule (T3-minimum): issue next tile's global_load_lds BEFORE the
// current tile's ds_read+MFMA; ONE barrier per K-step (its implicit
// vmcnt(0)+lgkmcnt(0) drain lands after ~450cy of useful work, not before it).
// LDS chunk-XOR bank swizzle via permuted GLOBAL source + matching ds_read.
__device__ __forceinline__ void gemm_tile(const u16* __restrict__ Ah, const u16* __restrict__ Al,
                                          const u16* __restrict__ Bh, const u16* __restrict__ Bl,
                                          int trow0, int col0, int tid, u16* sm, f32x4 (&acc)[4][4]) {
  int lane = tid & 63, wid = tid >> 6;
  int wr = wid >> 1, wc = wid & 1;

  int r_s = wid * 32 + (lane >> 2);
  int c_s = (((lane & 3) ^ ((lane >> 3) & 3)) << 3);
  int ar0 = trow0 + r_s, ar1 = ar0 + 16;   // trow0<=896, r_s<=111 -> in bounds
  int br0 = col0 + r_s, br1 = br0 + 16;

  int fr = lane & 15, fq = lane >> 4;
  int cswz = (fq ^ ((fr >> 1) & 3)) * 8;
  int a_off0 = (wr * 64 + fr) * 32 + cswz;
  int b_off0 = (wc * 64 + fr) * 32 + cswz;

  const size_t a0 = (size_t)ar0 * D_DIM + c_s, a1 = (size_t)ar1 * D_DIM + c_s;
  const size_t b0 = (size_t)br0 * D_DIM + c_s, b1 = (size_t)br1 * D_DIM + c_s;
  int wbase = wid * 1024;

#define STAGE(buf, kt)                                                   \
  do {                                                                   \
    u16* bp = sm + (buf) * 16384;                                        \
    int k0 = (kt) * 32;                                                  \
    gl16(Ah + a0 + k0, &bp[wbase]);                                      \
    gl16(Ah + a1 + k0, &bp[wbase + 512]);                                \
    gl16(Al + a0 + k0, &bp[4096 + wbase]);                               \
    gl16(Al + a1 + k0, &bp[4096 + wbase + 512]);                         \
    gl16(Bh + b0 + k0, &bp[8192 + wbase]);                               \
    gl16(Bh + b1 + k0, &bp[8192 + wbase + 512]);                         \
    gl16(Bl + b0 + k0, &bp[12288 + wbase]);                              \
    gl16(Bl + b1 + k0, &bp[12288 + wbase + 512]);                        \
  } while (0)

  STAGE(0, 0);
  __syncthreads();
#pragma unroll
  for (int kt = 0; kt < 8; ++kt) {
    int cur = kt & 1;
    if (kt < 7) STAGE(cur ^ 1, kt + 1);   // prefetch overlaps ds_read+MFMA below
    const u16* bp = sm + cur * 16384;
    bf16x8 ah[4], al[4], bh[4], bl[4];
#pragma unroll
    for (int m = 0; m < 4; ++m) {
      ah[m] = *(const bf16x8*)&bp[a_off0 + m * 512];
      al[m] = *(const bf16x8*)&bp[4096 + a_off0 + m * 512];
    }
#pragma unroll
    for (int n = 0; n < 4; ++n) {
      bh[n] = *(const bf16x8*)&bp[8192 + b_off0 + n * 512];
      bl[n] = *(const bf16x8*)&bp[12288 + b_off0 + n * 512];
    }
#pragma unroll
    for (int m = 0; m < 4; ++m)
#pragma unroll
      for (int n = 0; n < 4; ++n) {
        acc[m][n] = __builtin_amdgcn_mfma_f32_16x16x32_bf16(ah[m], bh[n], acc[m][n], 0, 0, 0);
        acc[m][n] = __builtin_amdgcn_mfma_f32_16x16x32_bf16(ah[m], bl[n], acc[m][n], 0, 0, 0);
        acc[m][n] = __builtin_amdgcn_mfma_f32_16x16x32_bf16(al[m], bh[n], acc[m][n], 0, 0, 0);
      }
    __syncthreads();  // implicit vmcnt(0): prefetch guaranteed landed; also
                      // orders buf reuse (all waves done reading buf[cur])
  }
#undef STAGE
}

// ---- kernel 3a: sample GEMM (cols 0..4095) -> dist_s ------------------------
__global__ __launch_bounds__(256) void gemm_s_k(const u16* __restrict__ Ah, const u16* __restrict__ Al,
                                                const u16* __restrict__ Bh, const u16* __restrict__ Bl,
                                                float* __restrict__ dist_s) {
  __shared__ u16 sm[32768];
  int tid = threadIdx.x;
  int trow0 = blockIdx.x << 7, col0 = blockIdx.y << 7;
  f32x4 acc[4][4] = {};
  gemm_tile(Ah, Al, Bh, Bl, trow0, col0, tid, sm, acc);
  int lane = tid & 63, wid = tid >> 6;
  int wr = wid >> 1, wc = wid & 1, fr = lane & 15, fq = lane >> 4;
#pragma unroll
  for (int m = 0; m < 4; ++m) {
    int rr = trow0 + wr * 64 + m * 16 + fq * 4;
#pragma unroll
    for (int n = 0; n < 4; ++n) {
      int cc = col0 + wc * 64 + n * 16 + fr;
#pragma unroll
      for (int r = 0; r < 4; ++r)
        dist_s[(size_t)(rr + r) * NCOLS_S + cc] = acc[m][n][r];
    }
  }
}

// ---- kernel 3b: per-row coarse threshold from sample ------------------------
// Per-wave histograms (4x1024) to cut LDS same-address atomic serialization
// (~6 hot bins take all 4096 increments).
__global__ __launch_bounds__(256) void thr_k(const float* __restrict__ dist_s,
                                             u32* __restrict__ tkeyA, u32* __restrict__ cnt) {
  __shared__ u32 h4[4][1024];   // 16 KB
  __shared__ u32 wtot[4];
  int row = blockIdx.x, tid = threadIdx.x, lane = tid & 63, w = tid >> 6;
  const float4* dp = (const float4*)(dist_s + (size_t)row * NCOLS_S);
  for (int j = tid; j < 4096; j += 256) ((u32*)h4)[j] = 0;
  __syncthreads();
#pragma unroll
  for (int j = 0; j < 4; ++j) {
    float4 v = dp[tid + (j << 8)];
    atomicAdd(&h4[w][fkey(v.x) >> 22], 1u);
    atomicAdd(&h4[w][fkey(v.y) >> 22], 1u);
    atomicAdd(&h4[w][fkey(v.z) >> 22], 1u);
    atomicAdd(&h4[w][fkey(v.w) >> 22], 1u);
  }
  __syncthreads();
  // combine 4 chunks per thread into suffix-scan input
  u32 b0 = tid * 4;
  u32 cs = 0;
#pragma unroll
  for (int q = 0; q < 4; ++q)
    cs += h4[0][b0 + q] + h4[1][b0 + q] + h4[2][b0 + q] + h4[3][b0 + q];
  u32 sfx = cs;
#pragma unroll
  for (int off = 1; off < 64; off <<= 1) {
    u32 t = __shfl_down(sfx, off);
    sfx += (lane + off < 64) ? t : 0u;
  }
  if (lane == 0) wtot[w] = sfx;
  __syncthreads();
  u32 woff = 0;
  for (int j = w + 1; j < 4; ++j) woff += wtot[j];
  u32 S = sfx + woff, Safter = S - cs;
  if (S >= ST_SAMP && Safter < ST_SAMP) {  // unique crossing chunk
    u32 cum = Safter;
    int bin = b0;
    for (int b = b0 + 3; b >= (int)b0; --b) {
      u32 hb = h4[0][b] + h4[1][b] + h4[2][b] + h4[3][b];
      if (cum + hb >= ST_SAMP) { bin = b; break; }
      cum += hb;
    }
    tkeyA[row] = ((u32)bin) << 22;
  }
  if (tid == 0) cnt[row] = 0;
}

// ---- kernel 4: main GEMM with filtering epilogue (no dist materialized) -----
// Survivors staged in LDS (reusing the dead GEMM staging buffer), flushed with
// ONE global atomicAdd per (row, block) by 128 parallel threads.
__global__ __launch_bounds__(256) void gemm_f_k(const u16* __restrict__ Ah, const u16* __restrict__ Al,
                                                const u16* __restrict__ Bh, const u16* __restrict__ Bl,
                                                const u32* __restrict__ tkeyA, u32* __restrict__ cnt,
                                                u64* __restrict__ cand, int cap) {
  __shared__ u16 sm[32768];   // GEMM dbuf staging; aliased as u64 sbuf[4096] after
  __shared__ u32 sT[128];
  __shared__ u32 rcnt[128], rbase[128], rcur[128];
  __shared__ u32 scnt;
  int tid = threadIdx.x;
  int bid = blockIdx.x;
  int swz = (bid & 7) * 512 + (bid >> 3);
  int trow0 = (swz & 7) << 7;   // row tile fastest: 8 row-tiles/col-tile on one XCD
  int col0 = (swz >> 3) << 7;
  if (tid < 128) { sT[tid] = tkeyA[trow0 + tid]; rcnt[tid] = 0; }
  if (tid == 0) scnt = 0;
  // (visibility guaranteed by gemm_tile's internal barriers)
  f32x4 acc[4][4] = {};
  gemm_tile(Ah, Al, Bh, Bl, trow0, col0, tid, sm, acc);

  u64* sbuf = (u64*)sm;  // buf0 region; dead after gemm_tile's final barrier
  int lane = tid & 63, wid = tid >> 6;
  int wr = wid >> 1, wc = wid & 1, fr = lane & 15, fq = lane >> 4;
#pragma unroll
  for (int m = 0; m < 4; ++m) {
    int lr0 = wr * 64 + m * 16 + fq * 4;
#pragma unroll
    for (int n = 0; n < 4; ++n) {
      int cc = col0 + wc * 64 + n * 16 + fr;
#pragma unroll
      for (int r = 0; r < 4; ++r) {
        u32 k = fkey(acc[m][n][r]);
        int lrow = lr0 + r;
        if (k >= sT[lrow]) {
          u32 s = atomicAdd(&scnt, 1u);
          if (s < (u32)SCAP) {  // LDS fast path (always, statistically)
            sbuf[s] = ((u64)k << 32) | ((u64)(u32)lrow << 16) | (u64)(u32)cc;
            atomicAdd(&rcnt[lrow], 1u);
          } else {              // overflow fallback: direct global
            int grow = trow0 + lrow;
            u32 s2 = atomicAdd(&cnt[grow], 1u);
            if (s2 < (u32)cap) cand[(size_t)grow * cap + s2] = ((u64)k << 32) | (u32)(~(u32)cc);
          }
        }
      }
    }
  }
  __syncthreads();
  if (tid < 128) {  // one global atomic per row, 128 in parallel
    u32 nr = rcnt[tid];
    rbase[tid] = nr ? atomicAdd(&cnt[trow0 + tid], nr) : 0u;
    rcur[tid] = 0;
  }
  __syncthreads();
  u32 total = min(scnt, (u32)SCAP);
  for (u32 i = tid; i < total; i += 256) {
    u64 e = sbuf[i];
    u32 lrow = (u32)(e >> 16) & 127u;
    u32 col = (u32)e & 0xffffu;
    u32 key = (u32)(e >> 32);
    u32 off = atomicAdd(&rcur[lrow], 1u);   // LDS
    u32 slot = rbase[lrow] + off;
    if (slot < (u32)cap)
      cand[(size_t)(trow0 + lrow) * cap + slot] = ((u64)key << 32) | (u32)(~col);
  }
}

// ---- kernel 5: per-row finish: fine hist + boundary rank + class scores -----
__global__ __launch_bounds__(1024) void topk2_k(const u64* __restrict__ cand, const u32* __restrict__ cnt,
                                                const u32* __restrict__ tkeyA, const int* __restrict__ labels,
                                                float* __restrict__ out, int cap) {
  __shared__ u32 fhist[2048];  // 8 KB
  __shared__ u32 wtot[16];
  __shared__ u64 bnd[2048];    // 16 KB boundary-bin members
  __shared__ float cls[16];
  __shared__ float den_s;
  __shared__ u32 bcnt_s, bstar_s, cab_s;
  __shared__ u64 maxp_s;
  int row = blockIdx.x, tid = threadIdx.x, lane = tid & 63, w = tid >> 6;
  u32 c = cnt[row];
  if (c > (u32)cap) c = (u32)cap;
  u32 tkey = tkeyA[row];
  const u64* cp = cand + (size_t)row * cap;

  fhist[tid] = 0; fhist[tid + 1024] = 0;
  if (tid < 16) cls[tid] = 0.f;
  if (tid == 0) { den_s = 0.f; bcnt_s = 0; bstar_s = 0; cab_s = 0; maxp_s = 0; }
  __syncthreads();

  // pass A: max + fine histogram (bin = (key - tkey) >> 14, clamped)
  u64 mp = 0;
  for (u32 i = tid; i < c; i += 1024) {
    u64 p = cp[i];
    mp = p > mp ? p : mp;
    u32 fb = ((u32)(p >> 32) - tkey) >> 14;
    if (fb > 2047u) fb = 2047u;
    atomicAdd(&fhist[fb], 1u);
  }
#pragma unroll
  for (int off = 32; off > 0; off >>= 1) {
    u64 t = __shfl_down(mp, off);
    mp = t > mp ? t : mp;
  }
  if (lane == 0) atomicMax((unsigned long long*)&maxp_s, (unsigned long long)mp);
  __syncthreads();
  float dmax = funkey((u32)(maxp_s >> 32));
  bool allin = (c <= K_TOP);

  if (!allin) {  // suffix-scan 2-bin chunks -> boundary bin b*, count_above
    u32 cs2 = fhist[2 * tid] + fhist[2 * tid + 1];
    u32 sfx = cs2;
#pragma unroll
    for (int off = 1; off < 64; off <<= 1) {
      u32 t = __shfl_down(sfx, off);
      sfx += (lane + off < 64) ? t : 0u;
    }
    if (lane == 0) wtot[w] = sfx;
    __syncthreads();
    u32 woff = 0;
    for (int j = w + 1; j < 16; ++j) woff += wtot[j];
    u32 S = sfx + woff, Safter = S - cs2;
    if (S >= K_TOP && Safter < K_TOP) {
      u32 cum = Safter;
      int bs = 2 * tid;
      u32 cabv = 0;
      for (int b = 2 * tid + 1; b >= 2 * tid; --b) {
        u32 hb = fhist[b];
        if (cum + hb >= K_TOP) { bs = b; cabv = cum; break; }
        cum += hb;
      }
      bstar_s = (u32)bs;
      cab_s = cabv;
    }
    __syncthreads();
  }
  u32 bstar = bstar_s;
  int Kp = K_TOP - (int)cab_s;

  // pass B: definite items accumulate; boundary-bin members -> LDS
  for (u32 i = tid; i < c; i += 1024) {
    u64 p = cp[i];
    u32 k = (u32)(p >> 32);
    u32 fb = (k - tkey) >> 14;
    if (fb > 2047u) fb = 2047u;
    if (allin || fb > bstar) {
      float wgt = __expf((funkey(k) - dmax) * INV_T);
      atomicAdd(&den_s, wgt);
      u32 col = ~(u32)(p & 0xffffffffu);
      atomicAdd(&cls[labels[col & 0xffff] & 15], wgt);
    } else if (fb == bstar) {
      u32 s2 = atomicAdd(&bcnt_s, 1u);
      if (s2 < 2048u) bnd[s2] = p;
    }
  }
  __syncthreads();
  if (!allin) {  // exact rank within boundary bin (packed compare: ties by idx)
    int bc = (int)min(bcnt_s, 2048u);
    for (int i = tid; i < bc; i += 1024) {
      u64 p = bnd[i];
      int r = 0;
      for (int j = 0; j < bc; ++j) r += (bnd[j] > p) ? 1 : 0;
      if (r < Kp) {
        u32 k = (u32)(p >> 32);
        float wgt = __expf((funkey(k) - dmax) * INV_T);
        atomicAdd(&den_s, wgt);
        u32 col = ~(u32)(p & 0xffffffffu);
        atomicAdd(&cls[labels[col & 0xffff] & 15], wgt);
      }
    }
    __syncthreads();
  }
  if (tid < N_CLASSES)
    out[(size_t)row * N_CLASSES + tid] = fminf(cls[tid] / den_s + 1e-5f, 1.0f);
}

// ---- host -------------------------------------------------------------------
extern "C" void kernel_launch(void* const* d_in, const int* in_sizes, int n_in,
                              void* d_out, int out_size, void* d_ws, size_t ws_size,
                              hipStream_t stream) {
  const float* x = (const float*)d_in[0];
  const float* mem = (const float*)d_in[1];
  const int* lbl = (const int*)d_in[2];
  float* out = (float*)d_out;

  char* w = (char*)d_ws;
  u16* mem_hi = (u16*)w;  w += (size_t)Q_N * D_DIM * 2;
  u16* mem_lo = (u16*)w;  w += (size_t)Q_N * D_DIM * 2;
  u16* x_hi = (u16*)w;    w += (size_t)B_ROWS * D_DIM * 2;
  u16* x_lo = (u16*)w;    w += (size_t)B_ROWS * D_DIM * 2;
  u32* tkeyA = (u32*)w;   w += (size_t)B_ROWS * 4;
  u32* cntA = (u32*)w;    w += (size_t)B_ROWS * 4;
  float* dist_s = (float*)w;  w += (size_t)B_ROWS * NCOLS_S * 4;
  u64* cand = (u64*)w;

  size_t used = (size_t)(w - (char*)d_ws);
  size_t avail = ws_size > used ? ws_size - used : 0;
  int cap = (int)(avail / ((size_t)B_ROWS * 8));
  if (cap > 12288) cap = 12288;
  if (cap < 1024) cap = 1024;  // statistically never needed below this

  xnorm_k<<<B_ROWS, 256, 0, stream>>>(x, x_hi, x_lo);
  mdecomp_k<<<2048, 256, 0, stream>>>((const float4*)mem, (ushort4*)mem_hi, (ushort4*)mem_lo,
                                      Q_N * D_DIM / 4);
  gemm_s_k<<<dim3(8, 32), 256, 0, stream>>>(x_hi, x_lo, mem_hi, mem_lo, dist_s);
  thr_k<<<B_ROWS, 256, 0, stream>>>(dist_s, tkeyA, cntA);
  gemm_f_k<<<4096, 256, 0, stream>>>(x_hi, x_lo, mem_hi, mem_lo, tkeyA, cntA, cand, cap);
  topk2_k<<<B_ROWS, 1024, 0, stream>>>(cand, cntA, tkeyA, lbl, out, cap);
}